// Round 4
// baseline (389.897 us; speedup 1.0000x reference)
//
#include <hip/hip_runtime.h>
#include <stdint.h>
#include <stddef.h>

// ============================================================================
// MHA block on gfx950, bf16 MFMA pipeline.  B=2,S=2048,D=1024,H=16,hd=64.
// R9 == R8 resubmit (R8 bench died to a container/acquire flake; source
// audited for hangs/OOB/misalignment -- none).  Rationale recap:
// R6/R7 (qkv 98-108us @ MfmaUtil ~9.5%): global_load_lds is tracked as an
// LDS-DMA hazard at object granularity, so the compute phase's ds_reads get
// a conservative vmcnt(0) no matter how the double buffer is expressed ->
// pipeline never engaged, paid the 3->2 blocks/CU LDS cost anyway.
//  - Prefetch switched to REGISTER staging (T14 / HK pattern): single 32KB
//    LDS buffer (3 blocks/CU again) + per-iter global_load_dwordx4 -> VGPRs
//    issued BEFORE compute, ds_write after the post-compute barrier (where
//    the compiler's mandatory vmcnt(0) drain lands anyway -> latency hides
//    under the MFMAs).  Plain loads carry no LDS-DMA hazard.
//  - sched_barrier(0) after load-issue pins loads above the MFMA cluster.
//  - Same transform in qkv, flash (LDS 34KB, 4 blocks/CU), oproj.
// Predictions: qkv ~50us @ MfmaUtil ~20%; total ~190-200us.
// MFMA layouts (verified m89/m91/m120):
//   A-frag: A[m=lane&15][k=(lane>>4)*8+j]  (16B/lane contiguous)
//   B-frag: B[k=(lane>>4)*8+j][n=lane&15] == row-major read of B^T tile
//   C/D:    col=lane&15, row=(lane>>4)*4+reg
// GEMM LDS fragment-major (BK=64): chunk(row,kc) = (row>>4)*128 + kc*16
//   + (row&15), kc = k>>3 in 0..7.  Stage short-offset for (w,l,q):
//   (w+4*(q&1))*1024 + (q>>1)*512 + l*8  (== chunk(row,kc)*8, verified).
// ============================================================================

typedef __bf16 bf16x8 __attribute__((ext_vector_type(8)));
typedef float  f32x4  __attribute__((ext_vector_type(4)));

__device__ __forceinline__ unsigned short f2b(float f) {
  union { float f; uint32_t u; } v; v.f = f;
  uint32_t u = v.u;
  return (unsigned short)((u + 0x7FFFu + ((u >> 16) & 1u)) >> 16);  // RNE
}

// ---------------- cast x f32 -> bf16 ----------------
__global__ void cast_kernel(const float* __restrict__ in,
                            unsigned short* __restrict__ out, int n4) {
  int i = blockIdx.x * blockDim.x + threadIdx.x;
  if (i >= n4) return;
  float4 v = ((const float4*)in)[i];
  ushort4 o;
  o.x = f2b(v.x); o.y = f2b(v.y); o.z = f2b(v.z); o.w = f2b(v.w);
  ((ushort4*)out)[i] = o;
}

// ---------------- cast all 4 weight matrices in one launch ----------------
__global__ void cast_w_kernel(const float* __restrict__ wq, const float* __restrict__ wk,
                              const float* __restrict__ wv, const float* __restrict__ wo,
                              unsigned short* __restrict__ wqkv,
                              unsigned short* __restrict__ wobf) {
  int i = blockIdx.x * blockDim.x + threadIdx.x;   // 0 .. 4*2^18-1
  const int sel = i >> 18, k = i & ((1 << 18) - 1);
  const float* src = (sel == 0) ? wq : (sel == 1) ? wk : (sel == 2) ? wv : wo;
  float4 v = ((const float4*)src)[k];
  ushort4 o;
  o.x = f2b(v.x); o.y = f2b(v.y); o.z = f2b(v.z); o.w = f2b(v.w);
  if (sel < 3) ((ushort4*)wqkv)[(size_t)sel * 262144 + k] = o;
  else         ((ushort4*)wobf)[k] = o;
}

// ---------------- fused QKV projection GEMM (+bias, +RoPE on q/k) ----------
// C[4096,3072] = Xbf[4096,1024] @ Wqkv[3072,1024]^T, 128x128 tiles, BK=64,
// reg-staged pipeline (T14), single 32KB LDS buffer.
// Output layouts:
//   q: [bh][2048][64] row-major (RoPE'd)
//   k: tiled frag-major: [bh][st=32][ chunk L = (d>>3)*64 + (s&63) ][8 of d]
//   v: V^T tiled frag-major: [bh][st=32][ chunk L = ((s&63)>>3)*64 + d ][8 of s]
__global__ __launch_bounds__(256) void qkv_gemm_kernel(
    const unsigned short* __restrict__ A,    // x_bf [4096][1024]
    const unsigned short* __restrict__ W,    // wqkv [3072][1024]
    const float* __restrict__ biasq, const float* __restrict__ biask,
    const float* __restrict__ biasv,
    const float* __restrict__ cp, const float* __restrict__ sp,  // [2048][32]
    unsigned short* __restrict__ qo,
    unsigned short* __restrict__ ko,
    unsigned short* __restrict__ vo)
{
  __shared__ __align__(16) unsigned short As[128 * 64];   // 16 KB
  __shared__ __align__(16) unsigned short Bs[128 * 64];   // 16 KB
  const int tid  = threadIdx.x;
  const int w    = tid >> 6, l = tid & 63;
  const int lm   = l & 15,  quad = l >> 4;
  const int nblk = blockIdx.x;               // 0..23
  const int m0   = blockIdx.y * 128;
  const int n0g  = nblk * 128;
  const int wm   = (w >> 1) * 64, wn = (w & 1) * 64;

  const f32x4 fzero = {0.f, 0.f, 0.f, 0.f};
  f32x4 acc[4][4];
#pragma unroll
  for (int i = 0; i < 4; ++i)
#pragma unroll
    for (int j = 0; j < 4; ++j) acc[i][j] = fzero;

  uint4 ra[4], rb[4];                        // staged tile (32 VGPR)
  auto load_regs = [&](int k0) {
#pragma unroll
    for (int q = 0; q < 4; ++q) {
      const int row = w * 16 + lm + (q & 1) * 64;
      const int kc  = quad + (q >> 1) * 4;
      ra[q] = *(const uint4*)(A + (size_t)(m0 + row) * 1024 + k0 + kc * 8);
      rb[q] = *(const uint4*)(W + (size_t)(n0g + row) * 1024 + k0 + kc * 8);
    }
  };
  auto write_lds = [&]() {
#pragma unroll
    for (int q = 0; q < 4; ++q) {
      const size_t off = (size_t)(w + 4 * (q & 1)) * 1024 + (size_t)(q >> 1) * 512 + (size_t)l * 8;
      *(uint4*)(As + off) = ra[q];
      *(uint4*)(Bs + off) = rb[q];
    }
  };
  auto compute_tile = [&]() {
#pragma unroll
    for (int kk = 0; kk < 2; ++kk) {
      bf16x8 af[4], bfc[4];
#pragma unroll
      for (int i = 0; i < 4; ++i)
        af[i] = *(const bf16x8*)(As + (size_t)((((w >> 1) * 4 + i) * 128 + kk * 64 + l)) * 8);
#pragma unroll
      for (int j = 0; j < 4; ++j)
        bfc[j] = *(const bf16x8*)(Bs + (size_t)((((w & 1) * 4 + j) * 128 + kk * 64 + l)) * 8);
#pragma unroll
      for (int i = 0; i < 4; ++i)
#pragma unroll
        for (int j = 0; j < 4; ++j)
          acc[i][j] = __builtin_amdgcn_mfma_f32_16x16x32_bf16(af[i], bfc[j], acc[i][j], 0, 0, 0);
    }
  };

  // T14 pipeline: loads for t+1 issued before compute(t); the post-compute
  // __syncthreads() is where the vmcnt drain lands (hidden under MFMAs).
  load_regs(0);
  write_lds();
  __syncthreads();
  for (int t = 0; t < 16; ++t) {
    if (t < 15) load_regs((t + 1) * 64);     // issue early (no LDS hazard)
    __builtin_amdgcn_sched_barrier(0);       // keep loads above the MFMAs
    compute_tile();
    __syncthreads();                         // all waves done reading LDS
    if (t < 15) {
      write_lds();                           // regs -> LDS (vmcnt drained)
      __syncthreads();                       // tile t+1 visible
    }
  }

  const int which = nblk >> 3;               // 0=q 1=k 2=v
  const int n0    = (nblk & 7) * 128;
  const float* bias = (which == 0) ? biasq : (which == 1) ? biask : biasv;
#pragma unroll
  for (int i = 0; i < 4; ++i) {
#pragma unroll
    for (int j = 0; j < 4; ++j) {
      const int n = n0 + wn + j * 16 + lm;
      const float bval = bias[n];
      const int h = n >> 6, d = n & 63;
      float vals[4];
#pragma unroll
      for (int r = 0; r < 4; ++r) {
        const int m = m0 + wm + i * 16 + quad * 4 + r;
        const int srow = m & 2047;
        float val = acc[i][j][r] + bval;
        if (which != 2) {
          const float c  = cp[srow * 32 + (d >> 1)];
          const float sn = sp[srow * 32 + (d >> 1)];
          const float part = __shfl_xor(val, 1, 64);
          val = (d & 1) ? (part * sn + val * c) : (val * c - part * sn);
        }
        vals[r] = val;
      }
      const int mbase = m0 + wm + i * 16 + quad * 4;   // 4 consecutive s
      const int b = mbase >> 11, s0 = mbase & 2047;
      const int bh = (b << 4) + h;
      if (which == 0) {
#pragma unroll
        for (int r = 0; r < 4; ++r)
          qo[((size_t)bh * 2048 + s0 + r) * 64 + d] = f2b(vals[r]);
      } else if (which == 1) {
        // tiled: base = (bh*32 + s>>6)*4096 + ((d>>3)*64 + (s&63))*8 + (d&7)
#pragma unroll
        for (int r = 0; r < 4; ++r) {
          const int s = s0 + r;
          ko[((size_t)bh * 32 + (s >> 6)) * 4096 +
             (size_t)(((d >> 3) * 64 + (s & 63))) * 8 + (d & 7)] = f2b(vals[r]);
        }
      } else {
        // V^T tiled, 4 consecutive s -> one uint2 (8B) store
        uint32_t w0 = (uint32_t)f2b(vals[0]) | ((uint32_t)f2b(vals[1]) << 16);
        uint32_t w1 = (uint32_t)f2b(vals[2]) | ((uint32_t)f2b(vals[3]) << 16);
        uint2 pk; pk.x = w0; pk.y = w1;
        *(uint2*)(vo + ((size_t)bh * 32 + (s0 >> 6)) * 4096 +
                  (size_t)((((s0 & 63) >> 3) * 64 + d)) * 8 + (s0 & 7)) = pk;
      }
    }
  }
}

// ---------------- flash attention ----------------
// grid (bh=32, 16); block 512 thr = 8 waves; wave w owns q-rows w*16..w*16+15.
// S^T = K*Q^T formulation: t in-lane, m = lane&15.
// Reg-staged K/V prefetch (T14), single-buffered 34KB LDS (4 blocks/CU).
__global__ __launch_bounds__(512, 4) void flash_kernel(
    const unsigned short* __restrict__ Q,    // [32][2048][64] row-major
    const unsigned short* __restrict__ K,    // tiled frag-major (see qkv)
    const unsigned short* __restrict__ VT,   // V^T tiled frag-major
    unsigned short* __restrict__ O)          // [2][2048][1024]
{
  constexpr int PSTRIDE = 72;                // Ps row stride (shorts)
  __shared__ __align__(16) unsigned short Ks[4096];   // 8 KB, chunk L = c*64 + t
  __shared__ __align__(16) unsigned short Vs[4096];   // 8 KB, chunk L = ct*64 + d
  __shared__ __align__(16) unsigned short Ps[128 * PSTRIDE];
  const int tid = threadIdx.x;
  const int w = tid >> 6, l = tid & 63, lm = l & 15, quad = l >> 4;
  const int bh = blockIdx.x, qb = 15 - blockIdx.y;   // heavy q-blocks first
  const int mrow_g = qb * 128 + w * 16 + lm;         // this lane's softmax row

  // Q fragment to registers: lane reads row (qb*128+w*16+lm), 8 d at quad*8
  const size_t qbase = ((size_t)bh * 2048 + (size_t)qb * 128) * 64;
  bf16x8 aq[2];
#pragma unroll
  for (int kc = 0; kc < 2; ++kc)
    aq[kc] = *(const bf16x8*)(Q + qbase + (size_t)(w * 16 + lm) * 64 + kc * 32 + quad * 8);

  const f32x4 fzero = {0.f, 0.f, 0.f, 0.f};
  f32x4 Oacc[4];
#pragma unroll
  for (int jo = 0; jo < 4; ++jo) Oacc[jo] = fzero;
  float m_i = -1e30f, l_i = 0.f;

  uint4 rk, rv;                              // staged K/V chunks (8 VGPR)
  auto load_regs = [&](int kt) {
    const size_t tbase = ((size_t)bh * 32 + kt) * 4096;
    rk = *(const uint4*)(K  + tbase + (size_t)tid * 8);
    rv = *(const uint4*)(VT + tbase + (size_t)tid * 8);
  };
  auto write_lds = [&]() {
    *(uint4*)(Ks + (size_t)tid * 8) = rk;
    *(uint4*)(Vs + (size_t)tid * 8) = rv;
  };

  // one K/V tile: QK^T -> online softmax -> O += P V
  auto kvtile = [&](int kt) {
    // S^T = K * Q^T : Sc[tb] holds t = tb*16+quad*4+r (rows), m = lm (col)
    f32x4 Sc[4];
#pragma unroll
    for (int tb = 0; tb < 4; ++tb) Sc[tb] = fzero;
#pragma unroll
    for (int kc = 0; kc < 2; ++kc) {
      bf16x8 ak[4];
#pragma unroll
      for (int tb = 0; tb < 4; ++tb)
        ak[tb] = *(const bf16x8*)(Ks + (size_t)(((kc * 4 + quad) * 64 + tb * 16 + lm)) * 8);
#pragma unroll
      for (int tb = 0; tb < 4; ++tb)
        Sc[tb] = __builtin_amdgcn_mfma_f32_16x16x32_bf16(ak[tb], aq[kc], Sc[tb], 0, 0, 0);
    }

    // scale + causal mask.  Mask needed iff tile's max t (kt*64+63) exceeds
    // this wave's MIN row (qb*128 + w*16).
    const bool needmask = (kt * 64 + 63 > qb * 128 + w * 16);
    const int  mrel = mrow_g - kt * 64;      // mask t-index > mrel
    float mx = -1e30f;
#pragma unroll
    for (int tb = 0; tb < 4; ++tb) {
#pragma unroll
      for (int r = 0; r < 4; ++r) {
        float s = Sc[tb][r] * 0.125f;        // 1/sqrt(64)
        if (needmask && (tb * 16 + quad * 4 + r > mrel)) s = -1e30f;
        Sc[tb][r] = s;
        mx = fmaxf(mx, s);
      }
    }
    mx = fmaxf(mx, __shfl_xor(mx, 16, 64));
    mx = fmaxf(mx, __shfl_xor(mx, 32, 64));
    const float mnew  = fmaxf(m_i, mx);
    const float alpha = __expf(m_i - mnew);
    m_i = mnew;

    // exp, pack 4 consecutive t -> b64 write into Ps[m][t]
    float ps = 0.f;
#pragma unroll
    for (int tb = 0; tb < 4; ++tb) {
      float p0 = __expf(Sc[tb][0] - mnew), p1 = __expf(Sc[tb][1] - mnew);
      float p2 = __expf(Sc[tb][2] - mnew), p3 = __expf(Sc[tb][3] - mnew);
      ps += (p0 + p1) + (p2 + p3);
      uint2 pk;
      pk.x = (uint32_t)f2b(p0) | ((uint32_t)f2b(p1) << 16);
      pk.y = (uint32_t)f2b(p2) | ((uint32_t)f2b(p3) << 16);
      *(uint2*)(Ps + (size_t)(w * 16 + lm) * PSTRIDE + tb * 16 + quad * 4) = pk;
    }
    ps += __shfl_xor(ps, 16, 64);
    ps += __shfl_xor(ps, 32, 64);
    l_i = l_i * alpha + ps;

    // rescale Oacc: alpha lives per m=lm; O rows are quad*4+r -> shuffle
    float af4[4];
#pragma unroll
    for (int r = 0; r < 4; ++r) af4[r] = __shfl(alpha, quad * 4 + r, 64);
#pragma unroll
    for (int jo = 0; jo < 4; ++jo)
#pragma unroll
      for (int r = 0; r < 4; ++r) Oacc[jo][r] *= af4[r];

    // O += P V  (wave-private Ps rows; lgkmcnt orders write->read in-wave)
#pragma unroll
    for (int kc = 0; kc < 2; ++kc) {
      bf16x8 ap = *(const bf16x8*)(Ps + (size_t)(w * 16 + lm) * PSTRIDE + kc * 32 + quad * 8);
      bf16x8 bv[4];
#pragma unroll
      for (int jo = 0; jo < 4; ++jo)
        bv[jo] = *(const bf16x8*)(Vs + (size_t)(((kc * 4 + quad) * 64 + jo * 16 + lm)) * 8);
#pragma unroll
      for (int jo = 0; jo < 4; ++jo)
        Oacc[jo] = __builtin_amdgcn_mfma_f32_16x16x32_bf16(ap, bv[jo], Oacc[jo], 0, 0, 0);
    }
  };

  const int nkv = 2 * qb + 2;
  load_regs(0);
  write_lds();
  __syncthreads();                           // tile 0 resident
  for (int kt = 0; kt < nkv; ++kt) {
    if (kt + 1 < nkv) load_regs(kt + 1);     // issue next K/V early
    __builtin_amdgcn_sched_barrier(0);       // keep loads above compute
    kvtile(kt);
    __syncthreads();                         // all waves done reading Ks/Vs
    if (kt + 1 < nkv) {
      write_lds();                           // regs -> LDS (vmcnt drained)
      __syncthreads();                       // tile kt+1 visible
    }
  }

  // epilogue: normalize, write o_bf (b, s, h*64+d)
  float lf[4];
#pragma unroll
  for (int r = 0; r < 4; ++r) lf[r] = 1.0f / __shfl(l_i, quad * 4 + r, 64);
  const int b = bh >> 4, h = bh & 15;
#pragma unroll
  for (int jo = 0; jo < 4; ++jo)
#pragma unroll
    for (int r = 0; r < 4; ++r) {
      const int s   = qb * 128 + w * 16 + quad * 4 + r;
      const int col = h * 64 + jo * 16 + lm;
      O[((size_t)b * 2048 + s) * 1024 + col] = f2b(Oacc[jo][r] * lf[r]);
    }
}

// ---------------- output projection GEMM ----------------
// out[4096,1024] = Obf[4096,1024] @ Wo[1024,1024]^T + bias (fp32 out).
// 64x128 tiles, BK=64, 512 blocks (2/CU), reg-staged pipeline (T14).
__global__ __launch_bounds__(256) void oproj_gemm_kernel(
    const unsigned short* __restrict__ A,    // o_bf [4096][1024]
    const unsigned short* __restrict__ W,    // wo_bf [1024][1024]
    const float* __restrict__ bias,
    float* __restrict__ out)
{
  __shared__ __align__(16) unsigned short As[64 * 64];    // 8 KB
  __shared__ __align__(16) unsigned short Bs[128 * 64];   // 16 KB
  const int tid = threadIdx.x;
  const int w = tid >> 6, l = tid & 63;
  const int lm = l & 15, quad = l >> 4;
  const int m0 = blockIdx.y * 64;
  const int n0 = blockIdx.x * 128;

  const f32x4 fzero = {0.f, 0.f, 0.f, 0.f};
  f32x4 acc[4][2];
#pragma unroll
  for (int i = 0; i < 4; ++i)
#pragma unroll
    for (int j = 0; j < 2; ++j) acc[i][j] = fzero;

  uint4 ra[2], rb[4];                        // staged tile (24 VGPR)
  auto load_regs = [&](int k0) {
    // A: 64 rows x 8 kc = 512 chunks; 2 per thread
#pragma unroll
    for (int q = 0; q < 2; ++q) {
      const int row = w * 16 + lm;
      const int kc  = quad + 4 * q;
      ra[q] = *(const uint4*)(A + (size_t)(m0 + row) * 1024 + k0 + kc * 8);
    }
    // B: 128 rows x 8 kc = 1024 chunks; 4 per thread
#pragma unroll
    for (int q = 0; q < 4; ++q) {
      const int row = w * 16 + lm + (q & 1) * 64;
      const int kc  = quad + 4 * (q >> 1);
      rb[q] = *(const uint4*)(W + (size_t)(n0 + row) * 1024 + k0 + kc * 8);
    }
  };
  auto write_lds = [&]() {
#pragma unroll
    for (int q = 0; q < 2; ++q)
      *(uint4*)(As + (size_t)w * 1024 + (size_t)q * 512 + (size_t)l * 8) = ra[q];
#pragma unroll
    for (int q = 0; q < 4; ++q)
      *(uint4*)(Bs + (size_t)(w + 4 * (q & 1)) * 1024 + (size_t)(q >> 1) * 512 + (size_t)l * 8) = rb[q];
  };
  auto compute_tile = [&]() {
#pragma unroll
    for (int kk = 0; kk < 2; ++kk) {
      bf16x8 af[4], bfc[2];
#pragma unroll
      for (int i = 0; i < 4; ++i)
        af[i] = *(const bf16x8*)(As + (size_t)((i * 128 + kk * 64 + l)) * 8);
#pragma unroll
      for (int j = 0; j < 2; ++j)
        bfc[j] = *(const bf16x8*)(Bs + (size_t)(((w * 2 + j) * 128 + kk * 64 + l)) * 8);
#pragma unroll
      for (int i = 0; i < 4; ++i)
#pragma unroll
        for (int j = 0; j < 2; ++j)
          acc[i][j] = __builtin_amdgcn_mfma_f32_16x16x32_bf16(af[i], bfc[j], acc[i][j], 0, 0, 0);
    }
  };

  load_regs(0);
  write_lds();
  __syncthreads();
  for (int t = 0; t < 16; ++t) {
    if (t < 15) load_regs((t + 1) * 64);
    __builtin_amdgcn_sched_barrier(0);
    compute_tile();
    __syncthreads();
    if (t < 15) {
      write_lds();
      __syncthreads();
    }
  }

#pragma unroll
  for (int i = 0; i < 4; ++i) {
#pragma unroll
    for (int j = 0; j < 2; ++j) {
      const int n = n0 + w * 32 + j * 16 + lm;
      const float bval = bias[n];
#pragma unroll
      for (int r = 0; r < 4; ++r) {
        const int m = m0 + i * 16 + quad * 4 + r;
        out[(size_t)m * 1024 + n] = acc[i][j][r] + bval;
      }
    }
  }
}

// ---------------- host launch ----------------
extern "C" void kernel_launch(void* const* d_in, const int* in_sizes, int n_in,
                              void* d_out, int out_size, void* d_ws, size_t ws_size,
                              hipStream_t stream) {
  (void)in_sizes; (void)n_in; (void)out_size; (void)ws_size;
  const float* x  = (const float*)d_in[0];
  const float* cp = (const float*)d_in[1];
  const float* sp = (const float*)d_in[2];
  const float* wq = (const float*)d_in[3];
  const float* bq = (const float*)d_in[4];
  const float* wk = (const float*)d_in[5];
  const float* bk = (const float*)d_in[6];
  const float* wv = (const float*)d_in[7];
  const float* bv = (const float*)d_in[8];
  const float* wo = (const float*)d_in[9];
  const float* bo = (const float*)d_in[10];
  float* out = (float*)d_out;

  unsigned short* xbf  = (unsigned short*)d_ws;          // 4M shorts
  unsigned short* wqkv = xbf  + (size_t)4 * 1024 * 1024; // 3M
  unsigned short* wobf = wqkv + (size_t)3 * 1024 * 1024; // 1M
  unsigned short* qbf  = wobf + (size_t)1 * 1024 * 1024; // 4M (bh,s,d)
  unsigned short* kbf  = qbf  + (size_t)4 * 1024 * 1024; // 4M (tiled frag-major)
  unsigned short* vbf  = kbf  + (size_t)4 * 1024 * 1024; // 4M (V^T tiled)
  unsigned short* obf  = vbf  + (size_t)4 * 1024 * 1024; // 4M (b,s,h*64+d)

  hipLaunchKernelGGL(cast_kernel, dim3(4096), dim3(256), 0, stream, x, xbf, 1048576);
  hipLaunchKernelGGL(cast_w_kernel, dim3(4096), dim3(256), 0, stream,
                     wq, wk, wv, wo, wqkv, wobf);

  hipLaunchKernelGGL(qkv_gemm_kernel, dim3(24, 32), dim3(256), 0, stream,
                     xbf, wqkv, bq, bk, bv, cp, sp, qbf, kbf, vbf);
  hipLaunchKernelGGL(flash_kernel, dim3(32, 16), dim3(512), 0, stream,
                     qbf, kbf, vbf, obf);
  hipLaunchKernelGGL(oproj_gemm_kernel, dim3(8, 64), dim3(256), 0, stream,
                     obf, wobf, bo, out);
}

// Round 5
// 355.543 us; speedup vs baseline: 1.0966x; 1.0966x over previous
//
#include <hip/hip_runtime.h>
#include <stdint.h>
#include <stddef.h>

// ============================================================================
// MHA block on gfx950, bf16 MFMA pipeline.  B=2,S=2048,D=1024,H=16,hd=64.
// R10: isolate the T14 experiment to qkv only.
//  - R9 post-mortem: qkv WRITE_SIZE 24.6->200MB = the staged ra[]/rb[]
//    (32 VGPR, live across the MFMA cluster) were spilled to scratch by the
//    default launch-bounds register cap (104 VGPR reported).  ~175MB of
//    spill round-trip per dispatch -> 189us.  T14's mechanism never ran.
//  - qkv: keep T14 reg-staging, add __launch_bounds__(256, 1) so the backend
//    may allocate ~140-180 VGPR (3 waves/SIMD = 12 waves/CU, >= R5's measured
//    occupancy) and keep the staged tile in registers.
//  - flash / oproj / casts: reverted to the proven R5 code (237us anchor) --
//    one variable this round; per-dispatch counters attribute cleanly.
// Predictions: qkv WRITE back to ~24.6MB, VGPR ~140-180, dur 45-58us
// (bounded at ~68us if overlap fails); total ~215-230us.
// MFMA layouts (verified m89/m91/m120):
//   A-frag: A[m=lane&15][k=(lane>>4)*8+j]  (16B/lane contiguous)
//   B-frag: B[k=(lane>>4)*8+j][n=lane&15] == row-major read of B^T tile
//   C/D:    col=lane&15, row=(lane>>4)*4+reg
// GEMM LDS fragment-major (BK=64): chunk(row,kc) = (row>>4)*128 + kc*16
//   + (row&15), kc = k>>3 in 0..7.  Stage short-offset for (w,l,q):
//   (w+4*(q&1))*1024 + (q>>1)*512 + l*8  (== chunk(row,kc)*8, verified).
// ============================================================================

typedef __bf16 bf16x8 __attribute__((ext_vector_type(8)));
typedef float  f32x4  __attribute__((ext_vector_type(4)));

__device__ __forceinline__ unsigned short f2b(float f) {
  union { float f; uint32_t u; } v; v.f = f;
  uint32_t u = v.u;
  return (unsigned short)((u + 0x7FFFu + ((u >> 16) & 1u)) >> 16);  // RNE
}

__device__ __forceinline__ void async16(const void* g, void* l) {
  __builtin_amdgcn_global_load_lds(
      (const __attribute__((address_space(1))) void*)g,
      (__attribute__((address_space(3))) void*)l, 16, 0, 0);
}

// ---------------- cast x f32 -> bf16 ----------------
__global__ void cast_kernel(const float* __restrict__ in,
                            unsigned short* __restrict__ out, int n4) {
  int i = blockIdx.x * blockDim.x + threadIdx.x;
  if (i >= n4) return;
  float4 v = ((const float4*)in)[i];
  ushort4 o;
  o.x = f2b(v.x); o.y = f2b(v.y); o.z = f2b(v.z); o.w = f2b(v.w);
  ((ushort4*)out)[i] = o;
}

// ---------------- cast all 4 weight matrices in one launch ----------------
__global__ void cast_w_kernel(const float* __restrict__ wq, const float* __restrict__ wk,
                              const float* __restrict__ wv, const float* __restrict__ wo,
                              unsigned short* __restrict__ wqkv,
                              unsigned short* __restrict__ wobf) {
  int i = blockIdx.x * blockDim.x + threadIdx.x;   // 0 .. 4*2^18-1
  const int sel = i >> 18, k = i & ((1 << 18) - 1);
  const float* src = (sel == 0) ? wq : (sel == 1) ? wk : (sel == 2) ? wv : wo;
  float4 v = ((const float4*)src)[k];
  ushort4 o;
  o.x = f2b(v.x); o.y = f2b(v.y); o.z = f2b(v.z); o.w = f2b(v.w);
  if (sel < 3) ((ushort4*)wqkv)[(size_t)sel * 262144 + k] = o;
  else         ((ushort4*)wobf)[k] = o;
}

// ---------------- fused QKV projection GEMM (+bias, +RoPE on q/k) ----------
// C[4096,3072] = Xbf[4096,1024] @ Wqkv[3072,1024]^T, 128x128 tiles, BK=64,
// reg-staged pipeline (T14), single 32KB LDS buffer, launch_bounds(256,1)
// so the staged tile stays in VGPRs (R9 spilled at the default cap).
// Output layouts:
//   q: [bh][2048][64] row-major (RoPE'd)
//   k: tiled frag-major: [bh][st=32][ chunk L = (d>>3)*64 + (s&63) ][8 of d]
//   v: V^T tiled frag-major: [bh][st=32][ chunk L = ((s&63)>>3)*64 + d ][8 of s]
__global__ __launch_bounds__(256, 1) void qkv_gemm_kernel(
    const unsigned short* __restrict__ A,    // x_bf [4096][1024]
    const unsigned short* __restrict__ W,    // wqkv [3072][1024]
    const float* __restrict__ biasq, const float* __restrict__ biask,
    const float* __restrict__ biasv,
    const float* __restrict__ cp, const float* __restrict__ sp,  // [2048][32]
    unsigned short* __restrict__ qo,
    unsigned short* __restrict__ ko,
    unsigned short* __restrict__ vo)
{
  __shared__ __align__(16) unsigned short As[128 * 64];   // 16 KB
  __shared__ __align__(16) unsigned short Bs[128 * 64];   // 16 KB
  const int tid  = threadIdx.x;
  const int w    = tid >> 6, l = tid & 63;
  const int lm   = l & 15,  quad = l >> 4;
  const int nblk = blockIdx.x;               // 0..23
  const int m0   = blockIdx.y * 128;
  const int n0g  = nblk * 128;
  const int wm   = (w >> 1) * 64, wn = (w & 1) * 64;

  const f32x4 fzero = {0.f, 0.f, 0.f, 0.f};
  f32x4 acc[4][4];
#pragma unroll
  for (int i = 0; i < 4; ++i)
#pragma unroll
    for (int j = 0; j < 4; ++j) acc[i][j] = fzero;

  uint4 ra[4], rb[4];                        // staged tile (32 VGPR)
  auto load_regs = [&](int k0) {
#pragma unroll
    for (int q = 0; q < 4; ++q) {
      const int row = w * 16 + lm + (q & 1) * 64;
      const int kc  = quad + (q >> 1) * 4;
      ra[q] = *(const uint4*)(A + (size_t)(m0 + row) * 1024 + k0 + kc * 8);
      rb[q] = *(const uint4*)(W + (size_t)(n0g + row) * 1024 + k0 + kc * 8);
    }
  };
  auto write_lds = [&]() {
#pragma unroll
    for (int q = 0; q < 4; ++q) {
      const size_t off = (size_t)(w + 4 * (q & 1)) * 1024 + (size_t)(q >> 1) * 512 + (size_t)l * 8;
      *(uint4*)(As + off) = ra[q];
      *(uint4*)(Bs + off) = rb[q];
    }
  };
  auto compute_tile = [&]() {
#pragma unroll
    for (int kk = 0; kk < 2; ++kk) {
      bf16x8 af[4], bfc[4];
#pragma unroll
      for (int i = 0; i < 4; ++i)
        af[i] = *(const bf16x8*)(As + (size_t)((((w >> 1) * 4 + i) * 128 + kk * 64 + l)) * 8);
#pragma unroll
      for (int j = 0; j < 4; ++j)
        bfc[j] = *(const bf16x8*)(Bs + (size_t)((((w & 1) * 4 + j) * 128 + kk * 64 + l)) * 8);
#pragma unroll
      for (int i = 0; i < 4; ++i)
#pragma unroll
        for (int j = 0; j < 4; ++j)
          acc[i][j] = __builtin_amdgcn_mfma_f32_16x16x32_bf16(af[i], bfc[j], acc[i][j], 0, 0, 0);
    }
  };

  // T14 pipeline: loads for t+1 issued before compute(t); the post-compute
  // __syncthreads() is where the vmcnt drain lands (hidden under MFMAs).
  load_regs(0);
  write_lds();
  __syncthreads();
  for (int t = 0; t < 16; ++t) {
    if (t < 15) load_regs((t + 1) * 64);     // issue early (no LDS hazard)
    __builtin_amdgcn_sched_barrier(0);       // keep loads above the MFMAs
    compute_tile();
    __syncthreads();                         // all waves done reading LDS
    if (t < 15) {
      write_lds();                           // regs -> LDS (vmcnt drained)
      __syncthreads();                       // tile t+1 visible
    }
  }

  const int which = nblk >> 3;               // 0=q 1=k 2=v
  const int n0    = (nblk & 7) * 128;
  const float* bias = (which == 0) ? biasq : (which == 1) ? biask : biasv;
#pragma unroll
  for (int i = 0; i < 4; ++i) {
#pragma unroll
    for (int j = 0; j < 4; ++j) {
      const int n = n0 + wn + j * 16 + lm;
      const float bval = bias[n];
      const int h = n >> 6, d = n & 63;
      float vals[4];
#pragma unroll
      for (int r = 0; r < 4; ++r) {
        const int m = m0 + wm + i * 16 + quad * 4 + r;
        const int srow = m & 2047;
        float val = acc[i][j][r] + bval;
        if (which != 2) {
          const float c  = cp[srow * 32 + (d >> 1)];
          const float sn = sp[srow * 32 + (d >> 1)];
          const float part = __shfl_xor(val, 1, 64);
          val = (d & 1) ? (part * sn + val * c) : (val * c - part * sn);
        }
        vals[r] = val;
      }
      const int mbase = m0 + wm + i * 16 + quad * 4;   // 4 consecutive s
      const int b = mbase >> 11, s0 = mbase & 2047;
      const int bh = (b << 4) + h;
      if (which == 0) {
#pragma unroll
        for (int r = 0; r < 4; ++r)
          qo[((size_t)bh * 2048 + s0 + r) * 64 + d] = f2b(vals[r]);
      } else if (which == 1) {
        // tiled: base = (bh*32 + s>>6)*4096 + ((d>>3)*64 + (s&63))*8 + (d&7)
#pragma unroll
        for (int r = 0; r < 4; ++r) {
          const int s = s0 + r;
          ko[((size_t)bh * 32 + (s >> 6)) * 4096 +
             (size_t)(((d >> 3) * 64 + (s & 63))) * 8 + (d & 7)] = f2b(vals[r]);
        }
      } else {
        // V^T tiled, 4 consecutive s -> one uint2 (8B) store
        uint32_t w0 = (uint32_t)f2b(vals[0]) | ((uint32_t)f2b(vals[1]) << 16);
        uint32_t w1 = (uint32_t)f2b(vals[2]) | ((uint32_t)f2b(vals[3]) << 16);
        uint2 pk; pk.x = w0; pk.y = w1;
        *(uint2*)(vo + ((size_t)bh * 32 + (s0 >> 6)) * 4096 +
                  (size_t)((((s0 & 63) >> 3) * 64 + d)) * 8 + (s0 & 7)) = pk;
      }
    }
  }
}

// ---------------- flash attention (R5-proven version) ----------------
// grid (bh=32, 16); block 512 thr = 8 waves; wave w owns q-rows w*16..w*16+15.
// S^T = K*Q^T formulation: t in-lane, m = lane&15.
__global__ __launch_bounds__(512, 4) void flash_kernel(
    const unsigned short* __restrict__ Q,    // [32][2048][64] row-major
    const unsigned short* __restrict__ K,    // tiled frag-major (see qkv)
    const unsigned short* __restrict__ VT,   // V^T tiled frag-major
    unsigned short* __restrict__ O)          // [2][2048][1024]
{
  constexpr int PSTRIDE = 72;                // Ps row stride (shorts)
  __shared__ unsigned short Ks[4096];        // 64x64 tile, chunk L = c*64 + t
  __shared__ unsigned short Vs[4096];        // V^T tile, chunk L = ct*64 + d
  __shared__ unsigned short Ps[128 * PSTRIDE];
  const int tid = threadIdx.x;
  const int w = tid >> 6, l = tid & 63, lm = l & 15, quad = l >> 4;
  const int bh = blockIdx.x, qb = 15 - blockIdx.y;   // heavy q-blocks first
  const int mrow_g = qb * 128 + w * 16 + lm;         // this lane's softmax row

  // Q fragment to registers: lane reads row (qb*128+w*16+lm), 8 d at quad*8
  const size_t qbase = ((size_t)bh * 2048 + (size_t)qb * 128) * 64;
  bf16x8 aq[2];
#pragma unroll
  for (int kc = 0; kc < 2; ++kc)
    aq[kc] = *(const bf16x8*)(Q + qbase + (size_t)(w * 16 + lm) * 64 + kc * 32 + quad * 8);

  const f32x4 fzero = {0.f, 0.f, 0.f, 0.f};
  f32x4 Oacc[4];
#pragma unroll
  for (int jo = 0; jo < 4; ++jo) Oacc[jo] = fzero;
  float m_i = -1e30f, l_i = 0.f;

  const int nkv = 2 * qb + 2;
  for (int kt = 0; kt < nkv; ++kt) {
    __syncthreads();                         // prev iter done reading Ks/Vs
    {
      const size_t tbase = ((size_t)bh * 32 + kt) * 4096;
      async16(K  + tbase + (size_t)tid * 8, Ks + (size_t)w * 512);
      async16(VT + tbase + (size_t)tid * 8, Vs + (size_t)w * 512);
    }
    __syncthreads();                         // tiles in LDS

    // S^T = K * Q^T : Sc[tb] holds t = tb*16+quad*4+r (rows), m = lm (col)
    f32x4 Sc[4];
#pragma unroll
    for (int tb = 0; tb < 4; ++tb) Sc[tb] = fzero;
#pragma unroll
    for (int kc = 0; kc < 2; ++kc) {
      bf16x8 ak[4];
#pragma unroll
      for (int tb = 0; tb < 4; ++tb)
        ak[tb] = *(const bf16x8*)(Ks + (size_t)(((kc * 4 + quad) * 64 + tb * 16 + lm)) * 8);
#pragma unroll
      for (int tb = 0; tb < 4; ++tb)
        Sc[tb] = __builtin_amdgcn_mfma_f32_16x16x32_bf16(ak[tb], aq[kc], Sc[tb], 0, 0, 0);
    }

    // scale + causal mask.  Mask needed iff tile's max t (kt*64+63) exceeds
    // this wave's MIN row (qb*128 + w*16).
    const bool needmask = (kt * 64 + 63 > qb * 128 + w * 16);
    const int  mrel = mrow_g - kt * 64;      // mask t-index > mrel
    float mx = -1e30f;
#pragma unroll
    for (int tb = 0; tb < 4; ++tb) {
#pragma unroll
      for (int r = 0; r < 4; ++r) {
        float s = Sc[tb][r] * 0.125f;        // 1/sqrt(64)
        if (needmask && (tb * 16 + quad * 4 + r > mrel)) s = -1e30f;
        Sc[tb][r] = s;
        mx = fmaxf(mx, s);
      }
    }
    mx = fmaxf(mx, __shfl_xor(mx, 16, 64));
    mx = fmaxf(mx, __shfl_xor(mx, 32, 64));
    const float mnew  = fmaxf(m_i, mx);
    const float alpha = __expf(m_i - mnew);
    m_i = mnew;

    // exp, pack 4 consecutive t -> b64 write into Ps[m][t]
    float ps = 0.f;
#pragma unroll
    for (int tb = 0; tb < 4; ++tb) {
      float p0 = __expf(Sc[tb][0] - mnew), p1 = __expf(Sc[tb][1] - mnew);
      float p2 = __expf(Sc[tb][2] - mnew), p3 = __expf(Sc[tb][3] - mnew);
      ps += (p0 + p1) + (p2 + p3);
      uint2 pk;
      pk.x = (uint32_t)f2b(p0) | ((uint32_t)f2b(p1) << 16);
      pk.y = (uint32_t)f2b(p2) | ((uint32_t)f2b(p3) << 16);
      *(uint2*)(Ps + (size_t)(w * 16 + lm) * PSTRIDE + tb * 16 + quad * 4) = pk;
    }
    ps += __shfl_xor(ps, 16, 64);
    ps += __shfl_xor(ps, 32, 64);
    l_i = l_i * alpha + ps;

    // rescale Oacc: alpha lives per m=lm; O rows are quad*4+r -> shuffle
    float af4[4];
#pragma unroll
    for (int r = 0; r < 4; ++r) af4[r] = __shfl(alpha, quad * 4 + r, 64);
#pragma unroll
    for (int jo = 0; jo < 4; ++jo)
#pragma unroll
      for (int r = 0; r < 4; ++r) Oacc[jo][r] *= af4[r];

    // O += P V  (wave-private Ps rows; lgkmcnt orders write->read in-wave)
#pragma unroll
    for (int kc = 0; kc < 2; ++kc) {
      bf16x8 ap = *(const bf16x8*)(Ps + (size_t)(w * 16 + lm) * PSTRIDE + kc * 32 + quad * 8);
      bf16x8 bv[4];
#pragma unroll
      for (int jo = 0; jo < 4; ++jo)
        bv[jo] = *(const bf16x8*)(Vs + (size_t)(((kc * 4 + quad) * 64 + jo * 16 + lm)) * 8);
#pragma unroll
      for (int jo = 0; jo < 4; ++jo)
        Oacc[jo] = __builtin_amdgcn_mfma_f32_16x16x32_bf16(ap, bv[jo], Oacc[jo], 0, 0, 0);
    }
  }

  // epilogue: normalize, write o_bf (b, s, h*64+d)
  float lf[4];
#pragma unroll
  for (int r = 0; r < 4; ++r) lf[r] = 1.0f / __shfl(l_i, quad * 4 + r, 64);
  const int b = bh >> 4, h = bh & 15;
#pragma unroll
  for (int jo = 0; jo < 4; ++jo)
#pragma unroll
    for (int r = 0; r < 4; ++r) {
      const int s   = qb * 128 + w * 16 + quad * 4 + r;
      const int col = h * 64 + jo * 16 + lm;
      O[((size_t)b * 2048 + s) * 1024 + col] = f2b(Oacc[jo][r] * lf[r]);
    }
}

// ---------------- output projection GEMM (R5-proven version) ----------------
// out[4096,1024] = Obf[4096,1024] @ Wo[1024,1024]^T + bias (fp32 out).
// 64x128 tiles, BK=64, 512 blocks (2/CU).  Wave w covers cols w*32..w*32+31.
__global__ __launch_bounds__(256) void oproj_gemm_kernel(
    const unsigned short* __restrict__ A,    // o_bf [4096][1024]
    const unsigned short* __restrict__ W,    // wo_bf [1024][1024]
    const float* __restrict__ bias,
    float* __restrict__ out)
{
  __shared__ unsigned short As[64 * 64];     // 8 KB
  __shared__ unsigned short Bs[128 * 64];    // 16 KB
  const int tid = threadIdx.x;
  const int w = tid >> 6, l = tid & 63;
  const int lm = l & 15, quad = l >> 4;
  const int m0 = blockIdx.y * 64;
  const int n0 = blockIdx.x * 128;

  const f32x4 fzero = {0.f, 0.f, 0.f, 0.f};
  f32x4 acc[4][2];
#pragma unroll
  for (int i = 0; i < 4; ++i)
#pragma unroll
    for (int j = 0; j < 2; ++j) acc[i][j] = fzero;

  for (int k0 = 0; k0 < 1024; k0 += 64) {
    __syncthreads();
    // A: 64 rows x 8 kc = 512 chunks; 2 per thread
#pragma unroll
    for (int q = 0; q < 2; ++q) {
      const int row = w * 16 + lm;
      const int kc  = quad + 4 * q;
      async16(A + (size_t)(m0 + row) * 1024 + k0 + kc * 8,
              As + ((size_t)w * 128 + 64 * q) * 8);
    }
    // B: 128 rows x 8 kc = 1024 chunks; 4 per thread
#pragma unroll
    for (int q = 0; q < 4; ++q) {
      const int row = w * 16 + lm + (q & 1) * 64;
      const int kc  = quad + 4 * (q >> 1);
      async16(W + (size_t)(n0 + row) * 1024 + k0 + kc * 8,
              Bs + ((size_t)(w + 4 * (q & 1)) * 128 + 64 * (q >> 1)) * 8);
    }
    __syncthreads();
#pragma unroll
    for (int kk = 0; kk < 2; ++kk) {
      bf16x8 af[4], bfc[2];
#pragma unroll
      for (int i = 0; i < 4; ++i)
        af[i] = *(const bf16x8*)(As + (size_t)((i * 128 + kk * 64 + l)) * 8);
#pragma unroll
      for (int j = 0; j < 2; ++j)
        bfc[j] = *(const bf16x8*)(Bs + (size_t)(((w * 2 + j) * 128 + kk * 64 + l)) * 8);
#pragma unroll
      for (int i = 0; i < 4; ++i)
#pragma unroll
        for (int j = 0; j < 2; ++j)
          acc[i][j] = __builtin_amdgcn_mfma_f32_16x16x32_bf16(af[i], bfc[j], acc[i][j], 0, 0, 0);
    }
  }

#pragma unroll
  for (int i = 0; i < 4; ++i) {
#pragma unroll
    for (int j = 0; j < 2; ++j) {
      const int n = n0 + w * 32 + j * 16 + lm;
      const float bval = bias[n];
#pragma unroll
      for (int r = 0; r < 4; ++r) {
        const int m = m0 + i * 16 + quad * 4 + r;
        out[(size_t)m * 1024 + n] = acc[i][j][r] + bval;
      }
    }
  }
}

// ---------------- host launch ----------------
extern "C" void kernel_launch(void* const* d_in, const int* in_sizes, int n_in,
                              void* d_out, int out_size, void* d_ws, size_t ws_size,
                              hipStream_t stream) {
  (void)in_sizes; (void)n_in; (void)out_size; (void)ws_size;
  const float* x  = (const float*)d_in[0];
  const float* cp = (const float*)d_in[1];
  const float* sp = (const float*)d_in[2];
  const float* wq = (const float*)d_in[3];
  const float* bq = (const float*)d_in[4];
  const float* wk = (const float*)d_in[5];
  const float* bk = (const float*)d_in[6];
  const float* wv = (const float*)d_in[7];
  const float* bv = (const float*)d_in[8];
  const float* wo = (const float*)d_in[9];
  const float* bo = (const float*)d_in[10];
  float* out = (float*)d_out;

  unsigned short* xbf  = (unsigned short*)d_ws;          // 4M shorts
  unsigned short* wqkv = xbf  + (size_t)4 * 1024 * 1024; // 3M
  unsigned short* wobf = wqkv + (size_t)3 * 1024 * 1024; // 1M
  unsigned short* qbf  = wobf + (size_t)1 * 1024 * 1024; // 4M (bh,s,d)
  unsigned short* kbf  = qbf  + (size_t)4 * 1024 * 1024; // 4M (tiled frag-major)
  unsigned short* vbf  = kbf  + (size_t)4 * 1024 * 1024; // 4M (V^T tiled)
  unsigned short* obf  = vbf  + (size_t)4 * 1024 * 1024; // 4M (b,s,h*64+d)

  hipLaunchKernelGGL(cast_kernel, dim3(4096), dim3(256), 0, stream, x, xbf, 1048576);
  hipLaunchKernelGGL(cast_w_kernel, dim3(4096), dim3(256), 0, stream,
                     wq, wk, wv, wo, wqkv, wobf);

  hipLaunchKernelGGL(qkv_gemm_kernel, dim3(24, 32), dim3(256), 0, stream,
                     xbf, wqkv, bq, bk, bv, cp, sp, qbf, kbf, vbf);
  hipLaunchKernelGGL(flash_kernel, dim3(32, 16), dim3(512), 0, stream,
                     qbf, kbf, vbf, obf);
  hipLaunchKernelGGL(oproj_gemm_kernel, dim3(8, 64), dim3(256), 0, stream,
                     obf, wobf, bo, out);
}

// Round 6
// 259.252 us; speedup vs baseline: 1.5039x; 1.3714x over previous
//
#include <hip/hip_runtime.h>
#include <stdint.h>
#include <stddef.h>

// ============================================================================
// MHA block on gfx950, bf16 MFMA pipeline.  B=2,S=2048,D=1024,H=16,hd=64.
// R11: qkv = T3 minimal 2-phase recipe, verbatim (m230/m228d proven form):
//   global_load_lds double-buffer (static ping/pong, 4 separate __shared__
//   arrays), per iter: stage(next) -> sched_barrier(0) [pin DMA issue ABOVE
//   the MFMA cluster -- R6's missing piece] -> compute(cur) -> inline-asm
//   s_waitcnt vmcnt(0) -> RAW s_barrier (not __syncthreads) ->
//   sched_barrier(0).  Stage/compute byte mappings identical to R5.
// R9/R10 post-mortem: T14 reg-staging placed ra[]/rb[] in scratch BEFORE
//   regalloc (VGPR stuck at 104 with launch_bounds(256,1); WRITE_SIZE 190MB)
//   -- SROA failure, not pressure.  T14-via-arrays abandoned.
// flash / oproj / casts: exact R5 (237us anchor).
// Predictions: qkv 45-58us (MfmaUtil 18-25%, WRITE ~24.6MB) on success;
//   ~100us repeat on failure (kills source-level pipelining for qkv).
// MFMA layouts (verified m89/m91/m120):
//   A-frag: A[m=lane&15][k=(lane>>4)*8+j]  (16B/lane contiguous)
//   B-frag: B[k=(lane>>4)*8+j][n=lane&15] == row-major read of B^T tile
//   C/D:    col=lane&15, row=(lane>>4)*4+reg
// GEMM LDS fragment-major (BK=64): chunk(row,kc) = (row>>4)*128 + kc*16
//   + (row&15), kc = k>>3 in 0..7.  Wave stage base = (w+4*(q&1))*128
//   + 64*(q>>1), lane at +l -> wave-uniform base + lane*16B for
//   global_load_lds; frag reads are lane-contiguous 1KB blocks.
// ============================================================================

typedef __bf16 bf16x8 __attribute__((ext_vector_type(8)));
typedef float  f32x4  __attribute__((ext_vector_type(4)));

__device__ __forceinline__ unsigned short f2b(float f) {
  union { float f; uint32_t u; } v; v.f = f;
  uint32_t u = v.u;
  return (unsigned short)((u + 0x7FFFu + ((u >> 16) & 1u)) >> 16);  // RNE
}

__device__ __forceinline__ void async16(const void* g, void* l) {
  __builtin_amdgcn_global_load_lds(
      (const __attribute__((address_space(1))) void*)g,
      (__attribute__((address_space(3))) void*)l, 16, 0, 0);
}

// ---------------- cast x f32 -> bf16 ----------------
__global__ void cast_kernel(const float* __restrict__ in,
                            unsigned short* __restrict__ out, int n4) {
  int i = blockIdx.x * blockDim.x + threadIdx.x;
  if (i >= n4) return;
  float4 v = ((const float4*)in)[i];
  ushort4 o;
  o.x = f2b(v.x); o.y = f2b(v.y); o.z = f2b(v.z); o.w = f2b(v.w);
  ((ushort4*)out)[i] = o;
}

// ---------------- cast all 4 weight matrices in one launch ----------------
__global__ void cast_w_kernel(const float* __restrict__ wq, const float* __restrict__ wk,
                              const float* __restrict__ wv, const float* __restrict__ wo,
                              unsigned short* __restrict__ wqkv,
                              unsigned short* __restrict__ wobf) {
  int i = blockIdx.x * blockDim.x + threadIdx.x;   // 0 .. 4*2^18-1
  const int sel = i >> 18, k = i & ((1 << 18) - 1);
  const float* src = (sel == 0) ? wq : (sel == 1) ? wk : (sel == 2) ? wv : wo;
  float4 v = ((const float4*)src)[k];
  ushort4 o;
  o.x = f2b(v.x); o.y = f2b(v.y); o.z = f2b(v.z); o.w = f2b(v.w);
  if (sel < 3) ((ushort4*)wqkv)[(size_t)sel * 262144 + k] = o;
  else         ((ushort4*)wobf)[k] = o;
}

// ---------------- fused QKV projection GEMM (+bias, +RoPE on q/k) ----------
// C[4096,3072] = Xbf[4096,1024] @ Wqkv[3072,1024]^T, 128x128 tiles, BK=64,
// T3 minimal 2-phase: gload_lds dbuf + raw s_barrier + asm vmcnt(0) +
// sched_barrier(0) pinning.
// Output layouts:
//   q: [bh][2048][64] row-major (RoPE'd)
//   k: tiled frag-major: [bh][st=32][ chunk L = (d>>3)*64 + (s&63) ][8 of d]
//   v: V^T tiled frag-major: [bh][st=32][ chunk L = ((s&63)>>3)*64 + d ][8 of s]
__global__ __launch_bounds__(256) void qkv_gemm_kernel(
    const unsigned short* __restrict__ A,    // x_bf [4096][1024]
    const unsigned short* __restrict__ W,    // wqkv [3072][1024]
    const float* __restrict__ biasq, const float* __restrict__ biask,
    const float* __restrict__ biasv,
    const float* __restrict__ cp, const float* __restrict__ sp,  // [2048][32]
    unsigned short* __restrict__ qo,
    unsigned short* __restrict__ ko,
    unsigned short* __restrict__ vo)
{
  __shared__ __align__(16) unsigned short As0[128 * 64];  // 16 KB
  __shared__ __align__(16) unsigned short Bs0[128 * 64];  // 16 KB
  __shared__ __align__(16) unsigned short As1[128 * 64];  // 16 KB
  __shared__ __align__(16) unsigned short Bs1[128 * 64];  // 16 KB
  const int tid  = threadIdx.x;
  const int w    = tid >> 6, l = tid & 63;
  const int lm   = l & 15,  quad = l >> 4;
  const int nblk = blockIdx.x;               // 0..23
  const int m0   = blockIdx.y * 128;
  const int n0g  = nblk * 128;
  const int wm   = (w >> 1) * 64, wn = (w & 1) * 64;

  const f32x4 fzero = {0.f, 0.f, 0.f, 0.f};
  f32x4 acc[4][4];
#pragma unroll
  for (int i = 0; i < 4; ++i)
#pragma unroll
    for (int j = 0; j < 4; ++j) acc[i][j] = fzero;

  auto stage = [&](unsigned short* Asb, unsigned short* Bsb, int k0) {
#pragma unroll
    for (int q = 0; q < 4; ++q) {
      const int row = w * 16 + lm + (q & 1) * 64;
      const int kc  = quad + (q >> 1) * 4;
      const size_t ldsb = ((size_t)(w + 4 * (q & 1)) * 128 + 64 * (q >> 1)) * 8;
      async16(A + (size_t)(m0 + row) * 1024 + k0 + kc * 8, Asb + ldsb);
      async16(W + (size_t)(n0g + row) * 1024 + k0 + kc * 8, Bsb + ldsb);
    }
  };
  auto comp = [&](const unsigned short* Asb, const unsigned short* Bsb) {
#pragma unroll
    for (int kk = 0; kk < 2; ++kk) {
      bf16x8 af[4], bfc[4];
#pragma unroll
      for (int i = 0; i < 4; ++i)
        af[i] = *(const bf16x8*)(Asb + (size_t)((((w >> 1) * 4 + i) * 128 + kk * 64 + l)) * 8);
#pragma unroll
      for (int j = 0; j < 4; ++j)
        bfc[j] = *(const bf16x8*)(Bsb + (size_t)((((w & 1) * 4 + j) * 128 + kk * 64 + l)) * 8);
#pragma unroll
      for (int i = 0; i < 4; ++i)
#pragma unroll
        for (int j = 0; j < 4; ++j)
          acc[i][j] = __builtin_amdgcn_mfma_f32_16x16x32_bf16(af[i], bfc[j], acc[i][j], 0, 0, 0);
    }
  };

  // ---- T3 minimal 2-phase pipeline ----
  stage(As0, Bs0, 0);
  asm volatile("s_waitcnt vmcnt(0)" ::: "memory");
  __builtin_amdgcn_s_barrier();
  __builtin_amdgcn_sched_barrier(0);
#pragma unroll 1
  for (int t = 0; t < 14; t += 2) {
    stage(As1, Bs1, (t + 1) * 64);           // next tile in flight...
    __builtin_amdgcn_sched_barrier(0);       // pin DMA issue above MFMAs
    comp(As0, Bs0);                          // ...hidden under this compute
    asm volatile("s_waitcnt vmcnt(0)" ::: "memory");
    __builtin_amdgcn_s_barrier();
    __builtin_amdgcn_sched_barrier(0);
    stage(As0, Bs0, (t + 2) * 64);
    __builtin_amdgcn_sched_barrier(0);
    comp(As1, Bs1);
    asm volatile("s_waitcnt vmcnt(0)" ::: "memory");
    __builtin_amdgcn_s_barrier();
    __builtin_amdgcn_sched_barrier(0);
  }
  stage(As1, Bs1, 15 * 64);
  __builtin_amdgcn_sched_barrier(0);
  comp(As0, Bs0);                            // tile 14
  asm volatile("s_waitcnt vmcnt(0)" ::: "memory");
  __builtin_amdgcn_s_barrier();
  __builtin_amdgcn_sched_barrier(0);
  comp(As1, Bs1);                            // tile 15 (no prefetch)

  const int which = nblk >> 3;               // 0=q 1=k 2=v
  const int n0    = (nblk & 7) * 128;
  const float* bias = (which == 0) ? biasq : (which == 1) ? biask : biasv;
#pragma unroll
  for (int i = 0; i < 4; ++i) {
#pragma unroll
    for (int j = 0; j < 4; ++j) {
      const int n = n0 + wn + j * 16 + lm;
      const float bval = bias[n];
      const int h = n >> 6, d = n & 63;
      float vals[4];
#pragma unroll
      for (int r = 0; r < 4; ++r) {
        const int m = m0 + wm + i * 16 + quad * 4 + r;
        const int srow = m & 2047;
        float val = acc[i][j][r] + bval;
        if (which != 2) {
          const float c  = cp[srow * 32 + (d >> 1)];
          const float sn = sp[srow * 32 + (d >> 1)];
          const float part = __shfl_xor(val, 1, 64);
          val = (d & 1) ? (part * sn + val * c) : (val * c - part * sn);
        }
        vals[r] = val;
      }
      const int mbase = m0 + wm + i * 16 + quad * 4;   // 4 consecutive s
      const int b = mbase >> 11, s0 = mbase & 2047;
      const int bh = (b << 4) + h;
      if (which == 0) {
#pragma unroll
        for (int r = 0; r < 4; ++r)
          qo[((size_t)bh * 2048 + s0 + r) * 64 + d] = f2b(vals[r]);
      } else if (which == 1) {
        // tiled: base = (bh*32 + s>>6)*4096 + ((d>>3)*64 + (s&63))*8 + (d&7)
#pragma unroll
        for (int r = 0; r < 4; ++r) {
          const int s = s0 + r;
          ko[((size_t)bh * 32 + (s >> 6)) * 4096 +
             (size_t)(((d >> 3) * 64 + (s & 63))) * 8 + (d & 7)] = f2b(vals[r]);
        }
      } else {
        // V^T tiled, 4 consecutive s -> one uint2 (8B) store
        uint32_t w0 = (uint32_t)f2b(vals[0]) | ((uint32_t)f2b(vals[1]) << 16);
        uint32_t w1 = (uint32_t)f2b(vals[2]) | ((uint32_t)f2b(vals[3]) << 16);
        uint2 pk; pk.x = w0; pk.y = w1;
        *(uint2*)(vo + ((size_t)bh * 32 + (s0 >> 6)) * 4096 +
                  (size_t)((((s0 & 63) >> 3) * 64 + d)) * 8 + (s0 & 7)) = pk;
      }
    }
  }
}

// ---------------- flash attention (R5-proven version) ----------------
// grid (bh=32, 16); block 512 thr = 8 waves; wave w owns q-rows w*16..w*16+15.
// S^T = K*Q^T formulation: t in-lane, m = lane&15.
__global__ __launch_bounds__(512, 4) void flash_kernel(
    const unsigned short* __restrict__ Q,    // [32][2048][64] row-major
    const unsigned short* __restrict__ K,    // tiled frag-major (see qkv)
    const unsigned short* __restrict__ VT,   // V^T tiled frag-major
    unsigned short* __restrict__ O)          // [2][2048][1024]
{
  constexpr int PSTRIDE = 72;                // Ps row stride (shorts)
  __shared__ unsigned short Ks[4096];        // 64x64 tile, chunk L = c*64 + t
  __shared__ unsigned short Vs[4096];        // V^T tile, chunk L = ct*64 + d
  __shared__ unsigned short Ps[128 * PSTRIDE];
  const int tid = threadIdx.x;
  const int w = tid >> 6, l = tid & 63, lm = l & 15, quad = l >> 4;
  const int bh = blockIdx.x, qb = 15 - blockIdx.y;   // heavy q-blocks first
  const int mrow_g = qb * 128 + w * 16 + lm;         // this lane's softmax row

  // Q fragment to registers: lane reads row (qb*128+w*16+lm), 8 d at quad*8
  const size_t qbase = ((size_t)bh * 2048 + (size_t)qb * 128) * 64;
  bf16x8 aq[2];
#pragma unroll
  for (int kc = 0; kc < 2; ++kc)
    aq[kc] = *(const bf16x8*)(Q + qbase + (size_t)(w * 16 + lm) * 64 + kc * 32 + quad * 8);

  const f32x4 fzero = {0.f, 0.f, 0.f, 0.f};
  f32x4 Oacc[4];
#pragma unroll
  for (int jo = 0; jo < 4; ++jo) Oacc[jo] = fzero;
  float m_i = -1e30f, l_i = 0.f;

  const int nkv = 2 * qb + 2;
  for (int kt = 0; kt < nkv; ++kt) {
    __syncthreads();                         // prev iter done reading Ks/Vs
    {
      const size_t tbase = ((size_t)bh * 32 + kt) * 4096;
      async16(K  + tbase + (size_t)tid * 8, Ks + (size_t)w * 512);
      async16(VT + tbase + (size_t)tid * 8, Vs + (size_t)w * 512);
    }
    __syncthreads();                         // tiles in LDS

    // S^T = K * Q^T : Sc[tb] holds t = tb*16+quad*4+r (rows), m = lm (col)
    f32x4 Sc[4];
#pragma unroll
    for (int tb = 0; tb < 4; ++tb) Sc[tb] = fzero;
#pragma unroll
    for (int kc = 0; kc < 2; ++kc) {
      bf16x8 ak[4];
#pragma unroll
      for (int tb = 0; tb < 4; ++tb)
        ak[tb] = *(const bf16x8*)(Ks + (size_t)(((kc * 4 + quad) * 64 + tb * 16 + lm)) * 8);
#pragma unroll
      for (int tb = 0; tb < 4; ++tb)
        Sc[tb] = __builtin_amdgcn_mfma_f32_16x16x32_bf16(ak[tb], aq[kc], Sc[tb], 0, 0, 0);
    }

    // scale + causal mask.  Mask needed iff tile's max t (kt*64+63) exceeds
    // this wave's MIN row (qb*128 + w*16).
    const bool needmask = (kt * 64 + 63 > qb * 128 + w * 16);
    const int  mrel = mrow_g - kt * 64;      // mask t-index > mrel
    float mx = -1e30f;
#pragma unroll
    for (int tb = 0; tb < 4; ++tb) {
#pragma unroll
      for (int r = 0; r < 4; ++r) {
        float s = Sc[tb][r] * 0.125f;        // 1/sqrt(64)
        if (needmask && (tb * 16 + quad * 4 + r > mrel)) s = -1e30f;
        Sc[tb][r] = s;
        mx = fmaxf(mx, s);
      }
    }
    mx = fmaxf(mx, __shfl_xor(mx, 16, 64));
    mx = fmaxf(mx, __shfl_xor(mx, 32, 64));
    const float mnew  = fmaxf(m_i, mx);
    const float alpha = __expf(m_i - mnew);
    m_i = mnew;

    // exp, pack 4 consecutive t -> b64 write into Ps[m][t]
    float ps = 0.f;
#pragma unroll
    for (int tb = 0; tb < 4; ++tb) {
      float p0 = __expf(Sc[tb][0] - mnew), p1 = __expf(Sc[tb][1] - mnew);
      float p2 = __expf(Sc[tb][2] - mnew), p3 = __expf(Sc[tb][3] - mnew);
      ps += (p0 + p1) + (p2 + p3);
      uint2 pk;
      pk.x = (uint32_t)f2b(p0) | ((uint32_t)f2b(p1) << 16);
      pk.y = (uint32_t)f2b(p2) | ((uint32_t)f2b(p3) << 16);
      *(uint2*)(Ps + (size_t)(w * 16 + lm) * PSTRIDE + tb * 16 + quad * 4) = pk;
    }
    ps += __shfl_xor(ps, 16, 64);
    ps += __shfl_xor(ps, 32, 64);
    l_i = l_i * alpha + ps;

    // rescale Oacc: alpha lives per m=lm; O rows are quad*4+r -> shuffle
    float af4[4];
#pragma unroll
    for (int r = 0; r < 4; ++r) af4[r] = __shfl(alpha, quad * 4 + r, 64);
#pragma unroll
    for (int jo = 0; jo < 4; ++jo)
#pragma unroll
      for (int r = 0; r < 4; ++r) Oacc[jo][r] *= af4[r];

    // O += P V  (wave-private Ps rows; lgkmcnt orders write->read in-wave)
#pragma unroll
    for (int kc = 0; kc < 2; ++kc) {
      bf16x8 ap = *(const bf16x8*)(Ps + (size_t)(w * 16 + lm) * PSTRIDE + kc * 32 + quad * 8);
      bf16x8 bv[4];
#pragma unroll
      for (int jo = 0; jo < 4; ++jo)
        bv[jo] = *(const bf16x8*)(Vs + (size_t)(((kc * 4 + quad) * 64 + jo * 16 + lm)) * 8);
#pragma unroll
      for (int jo = 0; jo < 4; ++jo)
        Oacc[jo] = __builtin_amdgcn_mfma_f32_16x16x32_bf16(ap, bv[jo], Oacc[jo], 0, 0, 0);
    }
  }

  // epilogue: normalize, write o_bf (b, s, h*64+d)
  float lf[4];
#pragma unroll
  for (int r = 0; r < 4; ++r) lf[r] = 1.0f / __shfl(l_i, quad * 4 + r, 64);
  const int b = bh >> 4, h = bh & 15;
#pragma unroll
  for (int jo = 0; jo < 4; ++jo)
#pragma unroll
    for (int r = 0; r < 4; ++r) {
      const int s   = qb * 128 + w * 16 + quad * 4 + r;
      const int col = h * 64 + jo * 16 + lm;
      O[((size_t)b * 2048 + s) * 1024 + col] = f2b(Oacc[jo][r] * lf[r]);
    }
}

// ---------------- output projection GEMM (R5-proven version) ----------------
// out[4096,1024] = Obf[4096,1024] @ Wo[1024,1024]^T + bias (fp32 out).
// 64x128 tiles, BK=64, 512 blocks (2/CU).  Wave w covers cols w*32..w*32+31.
__global__ __launch_bounds__(256) void oproj_gemm_kernel(
    const unsigned short* __restrict__ A,    // o_bf [4096][1024]
    const unsigned short* __restrict__ W,    // wo_bf [1024][1024]
    const float* __restrict__ bias,
    float* __restrict__ out)
{
  __shared__ unsigned short As[64 * 64];     // 8 KB
  __shared__ unsigned short Bs[128 * 64];    // 16 KB
  const int tid = threadIdx.x;
  const int w = tid >> 6, l = tid & 63;
  const int lm = l & 15, quad = l >> 4;
  const int m0 = blockIdx.y * 64;
  const int n0 = blockIdx.x * 128;

  const f32x4 fzero = {0.f, 0.f, 0.f, 0.f};
  f32x4 acc[4][2];
#pragma unroll
  for (int i = 0; i < 4; ++i)
#pragma unroll
    for (int j = 0; j < 2; ++j) acc[i][j] = fzero;

  for (int k0 = 0; k0 < 1024; k0 += 64) {
    __syncthreads();
    // A: 64 rows x 8 kc = 512 chunks; 2 per thread
#pragma unroll
    for (int q = 0; q < 2; ++q) {
      const int row = w * 16 + lm;
      const int kc  = quad + 4 * q;
      async16(A + (size_t)(m0 + row) * 1024 + k0 + kc * 8,
              As + ((size_t)w * 128 + 64 * q) * 8);
    }
    // B: 128 rows x 8 kc = 1024 chunks; 4 per thread
#pragma unroll
    for (int q = 0; q < 4; ++q) {
      const int row = w * 16 + lm + (q & 1) * 64;
      const int kc  = quad + 4 * (q >> 1);
      async16(W + (size_t)(n0 + row) * 1024 + k0 + kc * 8,
              Bs + ((size_t)(w + 4 * (q & 1)) * 128 + 64 * (q >> 1)) * 8);
    }
    __syncthreads();
#pragma unroll
    for (int kk = 0; kk < 2; ++kk) {
      bf16x8 af[4], bfc[2];
#pragma unroll
      for (int i = 0; i < 4; ++i)
        af[i] = *(const bf16x8*)(As + (size_t)((i * 128 + kk * 64 + l)) * 8);
#pragma unroll
      for (int j = 0; j < 2; ++j)
        bfc[j] = *(const bf16x8*)(Bs + (size_t)(((w * 2 + j) * 128 + kk * 64 + l)) * 8);
#pragma unroll
      for (int i = 0; i < 4; ++i)
#pragma unroll
        for (int j = 0; j < 2; ++j)
          acc[i][j] = __builtin_amdgcn_mfma_f32_16x16x32_bf16(af[i], bfc[j], acc[i][j], 0, 0, 0);
    }
  }

#pragma unroll
  for (int i = 0; i < 4; ++i) {
#pragma unroll
    for (int j = 0; j < 2; ++j) {
      const int n = n0 + w * 32 + j * 16 + lm;
      const float bval = bias[n];
#pragma unroll
      for (int r = 0; r < 4; ++r) {
        const int m = m0 + i * 16 + quad * 4 + r;
        out[(size_t)m * 1024 + n] = acc[i][j][r] + bval;
      }
    }
  }
}

// ---------------- host launch ----------------
extern "C" void kernel_launch(void* const* d_in, const int* in_sizes, int n_in,
                              void* d_out, int out_size, void* d_ws, size_t ws_size,
                              hipStream_t stream) {
  (void)in_sizes; (void)n_in; (void)out_size; (void)ws_size;
  const float* x  = (const float*)d_in[0];
  const float* cp = (const float*)d_in[1];
  const float* sp = (const float*)d_in[2];
  const float* wq = (const float*)d_in[3];
  const float* bq = (const float*)d_in[4];
  const float* wk = (const float*)d_in[5];
  const float* bk = (const float*)d_in[6];
  const float* wv = (const float*)d_in[7];
  const float* bv = (const float*)d_in[8];
  const float* wo = (const float*)d_in[9];
  const float* bo = (const float*)d_in[10];
  float* out = (float*)d_out;

  unsigned short* xbf  = (unsigned short*)d_ws;          // 4M shorts
  unsigned short* wqkv = xbf  + (size_t)4 * 1024 * 1024; // 3M
  unsigned short* wobf = wqkv + (size_t)3 * 1024 * 1024; // 1M
  unsigned short* qbf  = wobf + (size_t)1 * 1024 * 1024; // 4M (bh,s,d)
  unsigned short* kbf  = qbf  + (size_t)4 * 1024 * 1024; // 4M (tiled frag-major)
  unsigned short* vbf  = kbf  + (size_t)4 * 1024 * 1024; // 4M (V^T tiled)
  unsigned short* obf  = vbf  + (size_t)4 * 1024 * 1024; // 4M (b,s,h*64+d)

  hipLaunchKernelGGL(cast_kernel, dim3(4096), dim3(256), 0, stream, x, xbf, 1048576);
  hipLaunchKernelGGL(cast_w_kernel, dim3(4096), dim3(256), 0, stream,
                     wq, wk, wv, wo, wqkv, wobf);

  hipLaunchKernelGGL(qkv_gemm_kernel, dim3(24, 32), dim3(256), 0, stream,
                     xbf, wqkv, bq, bk, bv, cp, sp, qbf, kbf, vbf);
  hipLaunchKernelGGL(flash_kernel, dim3(32, 16), dim3(512), 0, stream,
                     qbf, kbf, vbf, obf);
  hipLaunchKernelGGL(oproj_gemm_kernel, dim3(8, 64), dim3(256), 0, stream,
                     obf, wobf, bo, out);
}

// Round 7
// 240.047 us; speedup vs baseline: 1.6243x; 1.0800x over previous
//
#include <hip/hip_runtime.h>
#include <stdint.h>
#include <stddef.h>

// ============================================================================
// MHA block on gfx950, bf16 MFMA pipeline.  B=2,S=2048,D=1024,H=16,hd=64.
// R12: attack shifts to flash (the ~130us dominant component).
//  - qkv/oproj/casts: exact R5 (proven: qkv 68.7us; R6/R7/R11 dbuf variants
//    all lose to it -- occupancy tax > pipeline gain at this geometry).
//  - flash: K/V LDS staging REMOVED (guide lesson #7: staging L2-fit data is
//    pure overhead).  kbf/vbf are stored frag-major, so each lane's MFMA
//    fragment is one coalesced 16B GLOBAL read at the same offset arithmetic
//    as the old LDS read.  The kv loop now has ZERO barriers: 8 waves stream
//    independently; TLP hides L2 latency; softmax VALU overlaps loads.
//    LDS = Ps only (18KB).  Per-bh K/V = 512KB, shared by 16 q-blocks ->
//    L2/L3-resident.
// Predictions: flash ~130 -> 70-85us (LDS 18432, MfmaUtil ~1.5x); qkv back
// to 68.7us/24.6MB writes; total ~180-200us.
// MFMA layouts (verified m89/m91/m120):
//   A-frag: A[m=lane&15][k=(lane>>4)*8+j]  (16B/lane contiguous)
//   B-frag: B[k=(lane>>4)*8+j][n=lane&15] == row-major read of B^T tile
//   C/D:    col=lane&15, row=(lane>>4)*4+reg
// GEMM LDS fragment-major (BK=64): chunk(row,kc) = (row>>4)*128 + kc*16
//   + (row&15), kc = k>>3 in 0..7.  Wave stage base = (w+4*(q&1))*128
//   + 64*(q>>1), lane at +l -> wave-uniform base + lane*16B for
//   global_load_lds; frag reads are lane-contiguous 1KB blocks.
// ============================================================================

typedef __bf16 bf16x8 __attribute__((ext_vector_type(8)));
typedef float  f32x4  __attribute__((ext_vector_type(4)));

__device__ __forceinline__ unsigned short f2b(float f) {
  union { float f; uint32_t u; } v; v.f = f;
  uint32_t u = v.u;
  return (unsigned short)((u + 0x7FFFu + ((u >> 16) & 1u)) >> 16);  // RNE
}

__device__ __forceinline__ void async16(const void* g, void* l) {
  __builtin_amdgcn_global_load_lds(
      (const __attribute__((address_space(1))) void*)g,
      (__attribute__((address_space(3))) void*)l, 16, 0, 0);
}

// ---------------- cast x f32 -> bf16 ----------------
__global__ void cast_kernel(const float* __restrict__ in,
                            unsigned short* __restrict__ out, int n4) {
  int i = blockIdx.x * blockDim.x + threadIdx.x;
  if (i >= n4) return;
  float4 v = ((const float4*)in)[i];
  ushort4 o;
  o.x = f2b(v.x); o.y = f2b(v.y); o.z = f2b(v.z); o.w = f2b(v.w);
  ((ushort4*)out)[i] = o;
}

// ---------------- cast all 4 weight matrices in one launch ----------------
__global__ void cast_w_kernel(const float* __restrict__ wq, const float* __restrict__ wk,
                              const float* __restrict__ wv, const float* __restrict__ wo,
                              unsigned short* __restrict__ wqkv,
                              unsigned short* __restrict__ wobf) {
  int i = blockIdx.x * blockDim.x + threadIdx.x;   // 0 .. 4*2^18-1
  const int sel = i >> 18, k = i & ((1 << 18) - 1);
  const float* src = (sel == 0) ? wq : (sel == 1) ? wk : (sel == 2) ? wv : wo;
  float4 v = ((const float4*)src)[k];
  ushort4 o;
  o.x = f2b(v.x); o.y = f2b(v.y); o.z = f2b(v.z); o.w = f2b(v.w);
  if (sel < 3) ((ushort4*)wqkv)[(size_t)sel * 262144 + k] = o;
  else         ((ushort4*)wobf)[k] = o;
}

// ---------------- fused QKV projection GEMM (+bias, +RoPE on q/k) ----------
// R5-proven version: 128x128 tiles, BK=64, single 32KB LDS, 2 barriers/iter.
// Output layouts:
//   q: [bh][2048][64] row-major (RoPE'd)
//   k: tiled frag-major: [bh][st=32][ chunk L = (d>>3)*64 + (s&63) ][8 of d]
//   v: V^T tiled frag-major: [bh][st=32][ chunk L = ((s&63)>>3)*64 + d ][8 of s]
__global__ __launch_bounds__(256) void qkv_gemm_kernel(
    const unsigned short* __restrict__ A,    // x_bf [4096][1024]
    const unsigned short* __restrict__ W,    // wqkv [3072][1024]
    const float* __restrict__ biasq, const float* __restrict__ biask,
    const float* __restrict__ biasv,
    const float* __restrict__ cp, const float* __restrict__ sp,  // [2048][32]
    unsigned short* __restrict__ qo,
    unsigned short* __restrict__ ko,
    unsigned short* __restrict__ vo)
{
  __shared__ unsigned short As[128 * 64];    // 16 KB
  __shared__ unsigned short Bs[128 * 64];    // 16 KB
  const int tid  = threadIdx.x;
  const int w    = tid >> 6, l = tid & 63;
  const int lm   = l & 15,  quad = l >> 4;
  const int nblk = blockIdx.x;               // 0..23
  const int m0   = blockIdx.y * 128;
  const int n0g  = nblk * 128;
  const int wm   = (w >> 1) * 64, wn = (w & 1) * 64;

  const f32x4 fzero = {0.f, 0.f, 0.f, 0.f};
  f32x4 acc[4][4];
#pragma unroll
  for (int i = 0; i < 4; ++i)
#pragma unroll
    for (int j = 0; j < 4; ++j) acc[i][j] = fzero;

  for (int k0 = 0; k0 < 1024; k0 += 64) {
    __syncthreads();                         // prev iter's ds_reads done
#pragma unroll
    for (int q = 0; q < 4; ++q) {
      const int row = w * 16 + lm + (q & 1) * 64;
      const int kc  = quad + (q >> 1) * 4;
      const size_t ldsb = ((size_t)(w + 4 * (q & 1)) * 128 + 64 * (q >> 1)) * 8;
      async16(A + (size_t)(m0 + row) * 1024 + k0 + kc * 8, As + ldsb);
      async16(W + (size_t)(n0g + row) * 1024 + k0 + kc * 8, Bs + ldsb);
    }
    __syncthreads();                         // drains vmcnt -> tile in LDS
#pragma unroll
    for (int kk = 0; kk < 2; ++kk) {
      bf16x8 af[4], bfc[4];
#pragma unroll
      for (int i = 0; i < 4; ++i)
        af[i] = *(const bf16x8*)(As + (size_t)((((w >> 1) * 4 + i) * 128 + kk * 64 + l)) * 8);
#pragma unroll
      for (int j = 0; j < 4; ++j)
        bfc[j] = *(const bf16x8*)(Bs + (size_t)((((w & 1) * 4 + j) * 128 + kk * 64 + l)) * 8);
#pragma unroll
      for (int i = 0; i < 4; ++i)
#pragma unroll
        for (int j = 0; j < 4; ++j)
          acc[i][j] = __builtin_amdgcn_mfma_f32_16x16x32_bf16(af[i], bfc[j], acc[i][j], 0, 0, 0);
    }
  }

  const int which = nblk >> 3;               // 0=q 1=k 2=v
  const int n0    = (nblk & 7) * 128;
  const float* bias = (which == 0) ? biasq : (which == 1) ? biask : biasv;
#pragma unroll
  for (int i = 0; i < 4; ++i) {
#pragma unroll
    for (int j = 0; j < 4; ++j) {
      const int n = n0 + wn + j * 16 + lm;
      const float bval = bias[n];
      const int h = n >> 6, d = n & 63;
      float vals[4];
#pragma unroll
      for (int r = 0; r < 4; ++r) {
        const int m = m0 + wm + i * 16 + quad * 4 + r;
        const int srow = m & 2047;
        float val = acc[i][j][r] + bval;
        if (which != 2) {
          const float c  = cp[srow * 32 + (d >> 1)];
          const float sn = sp[srow * 32 + (d >> 1)];
          const float part = __shfl_xor(val, 1, 64);
          val = (d & 1) ? (part * sn + val * c) : (val * c - part * sn);
        }
        vals[r] = val;
      }
      const int mbase = m0 + wm + i * 16 + quad * 4;   // 4 consecutive s
      const int b = mbase >> 11, s0 = mbase & 2047;
      const int bh = (b << 4) + h;
      if (which == 0) {
#pragma unroll
        for (int r = 0; r < 4; ++r)
          qo[((size_t)bh * 2048 + s0 + r) * 64 + d] = f2b(vals[r]);
      } else if (which == 1) {
        // tiled: base = (bh*32 + s>>6)*4096 + ((d>>3)*64 + (s&63))*8 + (d&7)
#pragma unroll
        for (int r = 0; r < 4; ++r) {
          const int s = s0 + r;
          ko[((size_t)bh * 32 + (s >> 6)) * 4096 +
             (size_t)(((d >> 3) * 64 + (s & 63))) * 8 + (d & 7)] = f2b(vals[r]);
        }
      } else {
        // V^T tiled, 4 consecutive s -> one uint2 (8B) store
        uint32_t w0 = (uint32_t)f2b(vals[0]) | ((uint32_t)f2b(vals[1]) << 16);
        uint32_t w1 = (uint32_t)f2b(vals[2]) | ((uint32_t)f2b(vals[3]) << 16);
        uint2 pk; pk.x = w0; pk.y = w1;
        *(uint2*)(vo + ((size_t)bh * 32 + (s0 >> 6)) * 4096 +
                  (size_t)((((s0 & 63) >> 3) * 64 + d)) * 8 + (s0 & 7)) = pk;
      }
    }
  }
}

// ---------------- flash attention (R12: barrier-free, K/V direct) ---------
// grid (bh=32, 16); block 512 thr = 8 waves; wave w owns q-rows w*16..w*16+15.
// S^T = K*Q^T formulation: t in-lane, m = lane&15.
// K/V read directly from global (frag-major layout == fragment per 16B lane
// read, coalesced 256B groups).  No K/V LDS, no barriers in the kv loop.
// LDS = Ps only (18KB).  Per-bh K/V (512KB) is L2-resident across the 16
// q-blocks that share it.
__global__ __launch_bounds__(512, 4) void flash_kernel(
    const unsigned short* __restrict__ Q,    // [32][2048][64] row-major
    const unsigned short* __restrict__ K,    // tiled frag-major (see qkv)
    const unsigned short* __restrict__ VT,   // V^T tiled frag-major
    unsigned short* __restrict__ O)          // [2][2048][1024]
{
  constexpr int PSTRIDE = 72;                // Ps row stride (shorts)
  __shared__ unsigned short Ps[128 * PSTRIDE];   // 18 KB (only LDS)
  const int tid = threadIdx.x;
  const int w = tid >> 6, l = tid & 63, lm = l & 15, quad = l >> 4;
  const int bh = blockIdx.x, qb = 15 - blockIdx.y;   // heavy q-blocks first
  const int mrow_g = qb * 128 + w * 16 + lm;         // this lane's softmax row

  // Q fragment to registers: lane reads row (qb*128+w*16+lm), 8 d at quad*8
  const size_t qbase = ((size_t)bh * 2048 + (size_t)qb * 128) * 64;
  bf16x8 aq[2];
#pragma unroll
  for (int kc = 0; kc < 2; ++kc)
    aq[kc] = *(const bf16x8*)(Q + qbase + (size_t)(w * 16 + lm) * 64 + kc * 32 + quad * 8);

  const f32x4 fzero = {0.f, 0.f, 0.f, 0.f};
  f32x4 Oacc[4];
#pragma unroll
  for (int jo = 0; jo < 4; ++jo) Oacc[jo] = fzero;
  float m_i = -1e30f, l_i = 0.f;

  const int nkv = 2 * qb + 2;
  for (int kt = 0; kt < nkv; ++kt) {
    const size_t tbase = ((size_t)bh * 32 + kt) * 4096;

    // S^T = K * Q^T : Sc[tb] holds t = tb*16+quad*4+r (rows), m = lm (col)
    // K fragments read DIRECTLY from global (same offsets as old LDS read).
    f32x4 Sc[4];
#pragma unroll
    for (int tb = 0; tb < 4; ++tb) Sc[tb] = fzero;
#pragma unroll
    for (int kc = 0; kc < 2; ++kc) {
      bf16x8 ak[4];
#pragma unroll
      for (int tb = 0; tb < 4; ++tb)
        ak[tb] = *(const bf16x8*)(K + tbase + (size_t)(((kc * 4 + quad) * 64 + tb * 16 + lm)) * 8);
#pragma unroll
      for (int tb = 0; tb < 4; ++tb)
        Sc[tb] = __builtin_amdgcn_mfma_f32_16x16x32_bf16(ak[tb], aq[kc], Sc[tb], 0, 0, 0);
    }

    // scale + causal mask.  Mask needed iff tile's max t (kt*64+63) exceeds
    // this wave's MIN row (qb*128 + w*16).
    const bool needmask = (kt * 64 + 63 > qb * 128 + w * 16);
    const int  mrel = mrow_g - kt * 64;      // mask t-index > mrel
    float mx = -1e30f;
#pragma unroll
    for (int tb = 0; tb < 4; ++tb) {
#pragma unroll
      for (int r = 0; r < 4; ++r) {
        float s = Sc[tb][r] * 0.125f;        // 1/sqrt(64)
        if (needmask && (tb * 16 + quad * 4 + r > mrel)) s = -1e30f;
        Sc[tb][r] = s;
        mx = fmaxf(mx, s);
      }
    }
    mx = fmaxf(mx, __shfl_xor(mx, 16, 64));
    mx = fmaxf(mx, __shfl_xor(mx, 32, 64));
    const float mnew  = fmaxf(m_i, mx);
    const float alpha = __expf(m_i - mnew);
    m_i = mnew;

    // exp, pack 4 consecutive t -> b64 write into Ps[m][t]
    float ps = 0.f;
#pragma unroll
    for (int tb = 0; tb < 4; ++tb) {
      float p0 = __expf(Sc[tb][0] - mnew), p1 = __expf(Sc[tb][1] - mnew);
      float p2 = __expf(Sc[tb][2] - mnew), p3 = __expf(Sc[tb][3] - mnew);
      ps += (p0 + p1) + (p2 + p3);
      uint2 pk;
      pk.x = (uint32_t)f2b(p0) | ((uint32_t)f2b(p1) << 16);
      pk.y = (uint32_t)f2b(p2) | ((uint32_t)f2b(p3) << 16);
      *(uint2*)(Ps + (size_t)(w * 16 + lm) * PSTRIDE + tb * 16 + quad * 4) = pk;
    }
    ps += __shfl_xor(ps, 16, 64);
    ps += __shfl_xor(ps, 32, 64);
    l_i = l_i * alpha + ps;

    // rescale Oacc: alpha lives per m=lm; O rows are quad*4+r -> shuffle
    float af4[4];
#pragma unroll
    for (int r = 0; r < 4; ++r) af4[r] = __shfl(alpha, quad * 4 + r, 64);
#pragma unroll
    for (int jo = 0; jo < 4; ++jo)
#pragma unroll
      for (int r = 0; r < 4; ++r) Oacc[jo][r] *= af4[r];

    // O += P V  (wave-private Ps rows; lgkmcnt orders write->read in-wave)
    // V fragments read DIRECTLY from global.
#pragma unroll
    for (int kc = 0; kc < 2; ++kc) {
      bf16x8 ap = *(const bf16x8*)(Ps + (size_t)(w * 16 + lm) * PSTRIDE + kc * 32 + quad * 8);
      bf16x8 bv[4];
#pragma unroll
      for (int jo = 0; jo < 4; ++jo)
        bv[jo] = *(const bf16x8*)(VT + tbase + (size_t)(((kc * 4 + quad) * 64 + jo * 16 + lm)) * 8);
#pragma unroll
      for (int jo = 0; jo < 4; ++jo)
        Oacc[jo] = __builtin_amdgcn_mfma_f32_16x16x32_bf16(ap, bv[jo], Oacc[jo], 0, 0, 0);
    }
  }

  // epilogue: normalize, write o_bf (b, s, h*64+d)
  float lf[4];
#pragma unroll
  for (int r = 0; r < 4; ++r) lf[r] = 1.0f / __shfl(l_i, quad * 4 + r, 64);
  const int b = bh >> 4, h = bh & 15;
#pragma unroll
  for (int jo = 0; jo < 4; ++jo)
#pragma unroll
    for (int r = 0; r < 4; ++r) {
      const int s   = qb * 128 + w * 16 + quad * 4 + r;
      const int col = h * 64 + jo * 16 + lm;
      O[((size_t)b * 2048 + s) * 1024 + col] = f2b(Oacc[jo][r] * lf[r]);
    }
}

// ---------------- output projection GEMM (R5-proven version) ----------------
// out[4096,1024] = Obf[4096,1024] @ Wo[1024,1024]^T + bias (fp32 out).
// 64x128 tiles, BK=64, 512 blocks (2/CU).  Wave w covers cols w*32..w*32+31.
__global__ __launch_bounds__(256) void oproj_gemm_kernel(
    const unsigned short* __restrict__ A,    // o_bf [4096][1024]
    const unsigned short* __restrict__ W,    // wo_bf [1024][1024]
    const float* __restrict__ bias,
    float* __restrict__ out)
{
  __shared__ unsigned short As[64 * 64];     // 8 KB
  __shared__ unsigned short Bs[128 * 64];    // 16 KB
  const int tid = threadIdx.x;
  const int w = tid >> 6, l = tid & 63;
  const int lm = l & 15, quad = l >> 4;
  const int m0 = blockIdx.y * 64;
  const int n0 = blockIdx.x * 128;

  const f32x4 fzero = {0.f, 0.f, 0.f, 0.f};
  f32x4 acc[4][2];
#pragma unroll
  for (int i = 0; i < 4; ++i)
#pragma unroll
    for (int j = 0; j < 2; ++j) acc[i][j] = fzero;

  for (int k0 = 0; k0 < 1024; k0 += 64) {
    __syncthreads();
    // A: 64 rows x 8 kc = 512 chunks; 2 per thread
#pragma unroll
    for (int q = 0; q < 2; ++q) {
      const int row = w * 16 + lm;
      const int kc  = quad + 4 * q;
      async16(A + (size_t)(m0 + row) * 1024 + k0 + kc * 8,
              As + ((size_t)w * 128 + 64 * q) * 8);
    }
    // B: 128 rows x 8 kc = 1024 chunks; 4 per thread
#pragma unroll
    for (int q = 0; q < 4; ++q) {
      const int row = w * 16 + lm + (q & 1) * 64;
      const int kc  = quad + 4 * (q >> 1);
      async16(W + (size_t)(n0 + row) * 1024 + k0 + kc * 8,
              Bs + ((size_t)(w + 4 * (q & 1)) * 128 + 64 * (q >> 1)) * 8);
    }
    __syncthreads();
#pragma unroll
    for (int kk = 0; kk < 2; ++kk) {
      bf16x8 af[4], bfc[2];
#pragma unroll
      for (int i = 0; i < 4; ++i)
        af[i] = *(const bf16x8*)(As + (size_t)((i * 128 + kk * 64 + l)) * 8);
#pragma unroll
      for (int j = 0; j < 2; ++j)
        bfc[j] = *(const bf16x8*)(Bs + (size_t)(((w * 2 + j) * 128 + kk * 64 + l)) * 8);
#pragma unroll
      for (int i = 0; i < 4; ++i)
#pragma unroll
        for (int j = 0; j < 2; ++j)
          acc[i][j] = __builtin_amdgcn_mfma_f32_16x16x32_bf16(af[i], bfc[j], acc[i][j], 0, 0, 0);
    }
  }

#pragma unroll
  for (int i = 0; i < 4; ++i) {
#pragma unroll
    for (int j = 0; j < 2; ++j) {
      const int n = n0 + w * 32 + j * 16 + lm;
      const float bval = bias[n];
#pragma unroll
      for (int r = 0; r < 4; ++r) {
        const int m = m0 + i * 16 + quad * 4 + r;
        out[(size_t)m * 1024 + n] = acc[i][j][r] + bval;
      }
    }
  }
}

// ---------------- host launch ----------------
extern "C" void kernel_launch(void* const* d_in, const int* in_sizes, int n_in,
                              void* d_out, int out_size, void* d_ws, size_t ws_size,
                              hipStream_t stream) {
  (void)in_sizes; (void)n_in; (void)out_size; (void)ws_size;
  const float* x  = (const float*)d_in[0];
  const float* cp = (const float*)d_in[1];
  const float* sp = (const float*)d_in[2];
  const float* wq = (const float*)d_in[3];
  const float* bq = (const float*)d_in[4];
  const float* wk = (const float*)d_in[5];
  const float* bk = (const float*)d_in[6];
  const float* wv = (const float*)d_in[7];
  const float* bv = (const float*)d_in[8];
  const float* wo = (const float*)d_in[9];
  const float* bo = (const float*)d_in[10];
  float* out = (float*)d_out;

  unsigned short* xbf  = (unsigned short*)d_ws;          // 4M shorts
  unsigned short* wqkv = xbf  + (size_t)4 * 1024 * 1024; // 3M
  unsigned short* wobf = wqkv + (size_t)3 * 1024 * 1024; // 1M
  unsigned short* qbf  = wobf + (size_t)1 * 1024 * 1024; // 4M (bh,s,d)
  unsigned short* kbf  = qbf  + (size_t)4 * 1024 * 1024; // 4M (tiled frag-major)
  unsigned short* vbf  = kbf  + (size_t)4 * 1024 * 1024; // 4M (V^T tiled)
  unsigned short* obf  = vbf  + (size_t)4 * 1024 * 1024; // 4M (b,s,h*64+d)

  hipLaunchKernelGGL(cast_kernel, dim3(4096), dim3(256), 0, stream, x, xbf, 1048576);
  hipLaunchKernelGGL(cast_w_kernel, dim3(4096), dim3(256), 0, stream,
                     wq, wk, wv, wo, wqkv, wobf);

  hipLaunchKernelGGL(qkv_gemm_kernel, dim3(24, 32), dim3(256), 0, stream,
                     xbf, wqkv, bq, bk, bv, cp, sp, qbf, kbf, vbf);
  hipLaunchKernelGGL(flash_kernel, dim3(32, 16), dim3(512), 0, stream,
                     qbf, kbf, vbf, obf);
  hipLaunchKernelGGL(oproj_gemm_kernel, dim3(8, 64), dim3(256), 0, stream,
                     obf, wobf, bo, out);
}